// Round 1
// baseline (1198.649 us; speedup 1.0000x reference)
//
#include <hip/hip_runtime.h>
#include <math.h>

// PQLayer forward, MI355X — R8.
//   x: (B,512) fp32   C: (64,256,8) fp32
//   out0 x_hat (B,512) = C[m,k*,:]   out1 codes (B,64,256) = one_hot(k*)
//
// Model (R4-R7 algebra): dur = F(~707us harness tax) + t1 + t2.
//   t2 ~200us = HBM floor (1.07 GB codes write, mandatory). t1 is the lever.
//   R5->R7: t1 is ISSUE-bound (scalar 300 -> packed 180 tracked the VALU cut);
//   pure-VALU arithmetic predicts ~40us, so VMEM issue + loop overhead own a
//   large share of K1's slots.
//
// R8 (K1 only; K2 bit-frozen from R4): two b-rows per thread. Keeps the R5
// invariant (m block-uniform -> C[m] 8KB L1-hot; R6 regressed by breaking
// THIS, not by multi-chain ILP). Halves VMEM instrs per dot (one ca/cb pair
// feeds two dots), halves loop overhead, doubles independent argmax chains.
// Per-row arithmetic bit-identical: P=xa*ca, Q=xb*cb, T=P+Q,
// dot=(T.x+T.y)+(T.z+T.w), contract off, strict > = first-max tie-break.
// Unroll 8->4 to hold VGPR <=64 (8192 waves need 8/SIMD residency).

#define B_SZ   16384
#define FEAT   512
#define M_SZ   64
#define K_SZ   256
#define D_SZ   8

typedef float v4f __attribute__((ext_vector_type(4)));

// ---------------- K1: packed argmax, 2 rows/thread, wide C loads ----------------
// 2048 blocks x 256 threads; block = (m, chunk of 512 b); thread = rows b, b+256.
__global__ __launch_bounds__(256) void pq_argmax(
    const float* __restrict__ x,
    const float* __restrict__ C,
    unsigned char* __restrict__ bestk8)   // [B][M]
{
#pragma clang fp contract(off)   // np einsum: separate product roundings, no FMA

    const int m     = blockIdx.x & (M_SZ - 1);   // block-uniform -> C[m] L1-hot
    const int chunk = blockIdx.x >> 6;           // 0..31
    const int b0    = (chunk << 9) | threadIdx.x;   // chunk*512 + tid
    const int b1    = b0 | 256;                     // second row, +256

    const float* xp0 = x + (size_t)b0 * FEAT + m * D_SZ;
    const float* xp1 = x + (size_t)b1 * FEAT + m * D_SZ;
    const v4f xa0 = ((const v4f*)xp0)[0];   // (x0..x3) row 0
    const v4f xb0 = ((const v4f*)xp0)[1];   // (x4..x7) row 0
    const v4f xa1 = ((const v4f*)xp1)[0];   // row 1
    const v4f xb1 = ((const v4f*)xp1)[1];

    const float* __restrict__ Cm = C + (size_t)m * (K_SZ * D_SZ);

    float best0 = -INFINITY, best1 = -INFINITY;
    int   bk0 = 0,           bk1 = 0;

#pragma unroll 4
    for (int k = 0; k < K_SZ; ++k) {
        const v4f* cr = (const v4f*)(Cm + k * D_SZ);  // 32B-aligned, uniform
        const v4f ca = cr[0];             // one dwordx4 load, feeds BOTH rows
        const v4f cb = cr[1];

        // row 0 — bit-exact np tree
        v4f P0 = xa0 * ca;                // v_pk_mul_f32 x2
        v4f Q0 = xb0 * cb;
        v4f T0 = P0 + Q0;                 // v_pk_add_f32 x2
        float d0 = (T0.x + T0.y) + (T0.z + T0.w);

        // row 1 — independent chain (ILP), same tree
        v4f P1 = xa1 * ca;
        v4f Q1 = xb1 * cb;
        v4f T1 = P1 + Q1;
        float d1 = (T1.x + T1.y) + (T1.z + T1.w);

        if (d0 > best0) { best0 = d0; bk0 = k; }  // strict >: first max
        if (d1 > best1) { best1 = d1; bk1 = k; }
    }

    bestk8[(size_t)b0 * M_SZ + m] = (unsigned char)bk0;  // L2 merges bytes
    bestk8[(size_t)b1 * M_SZ + m] = (unsigned char)bk1;
}

// ---------------- K2: fill-shaped writer (bit-frozen from R4) ----------------
// 4096 blocks x 256 threads; block owns b rows [4*blk, 4*blk+4) = 256 KB slab.
__global__ __launch_bounds__(256) void pq_fill(
    const float* __restrict__ C,
    const unsigned char* __restrict__ bestk8,  // [B][M]
    float* __restrict__ xhat,
    float* __restrict__ codes)
{
    const int t    = threadIdx.x;
    const int b0   = blockIdx.x << 2;
    const int w    = t >> 6;         // wave 0..3
    const int lane = t & 63;

    __shared__ unsigned char lbk[4 * M_SZ];

    lbk[t] = bestk8[(size_t)b0 * M_SZ + t];

    // xhat: wave w -> row b0+w, lane -> m. Coalesced 2KB/wave.
    {
        const int b  = b0 + w;
        const int kb = (int)bestk8[(size_t)b * M_SZ + lane];
        const float* cw = C + ((size_t)lane * K_SZ + kb) * D_SZ;
        const float4 h0 = ((const float4*)cw)[0];
        const float4 h1 = ((const float4*)cw)[1];
        float* xh = xhat + (size_t)b * FEAT + lane * D_SZ;
        ((float4*)xh)[0] = h0;
        ((float4*)xh)[1] = h1;
    }

    __syncthreads();

    // codes slab: 64 float4 stores/thread, one-hot folded in-stream.
    const int lane4 = lane << 2;
    float4* const slab = (float4*)(codes + (size_t)b0 * (M_SZ * K_SZ));

#pragma unroll 4
    for (int j = 0; j < 64; ++j) {
        const int r  = j >> 4;
        const int mj = (w + 4 * j) & 63;
        const int kk = (int)lbk[(r << 6) | mj];   // LDS broadcast (uniform)
        float4 v;
        v.x = (kk == lane4 + 0) ? 1.0f : 0.0f;
        v.y = (kk == lane4 + 1) ? 1.0f : 0.0f;
        v.z = (kk == lane4 + 2) ? 1.0f : 0.0f;
        v.w = (kk == lane4 + 3) ? 1.0f : 0.0f;
        slab[t + 256 * j] = v;
    }
}

extern "C" void kernel_launch(void* const* d_in, const int* in_sizes, int n_in,
                              void* d_out, int out_size, void* d_ws, size_t ws_size,
                              hipStream_t stream)
{
    const float* x = (const float*)d_in[0];
    const float* C = (const float*)d_in[1];
    float* xhat  = (float*)d_out;                           // (B, 512)
    float* codes = (float*)d_out + (size_t)B_SZ * FEAT;     // (B, 64, 256)
    unsigned char* bestk8 = (unsigned char*)d_ws;           // [B][M] u8 = 1 MB

    hipLaunchKernelGGL(pq_argmax, dim3(2048), dim3(256), 0, stream, x, C, bestk8);
    hipLaunchKernelGGL(pq_fill,   dim3(4096), dim3(256), 0, stream, C, bestk8, xhat, codes);
}

// Round 2
// 1193.106 us; speedup vs baseline: 1.0046x; 1.0046x over previous
//
#include <hip/hip_runtime.h>
#include <math.h>

// PQLayer forward, MI355X — R9.
//   x: (B,512) fp32   C: (64,256,8) fp32
//   out0 x_hat (B,512) = C[m,k*,:]   out1 codes (B,64,256) = one_hot(k*)
//
// Model: dur = F(~703us harness poison-fill, HBM-floor, non-actionable)
//            + t1(argmax) + t2(fill ~175-200us HBM write floor) + ~100us
//              small-memset/gap tax.
// R8 post-mortem: 2-rows/thread (half VMEM, 2x ILP) was NEUTRAL -> K1 is not
// issue-bound at the margin. Issue floor is ~45us; t1~180us. Revised theory:
// C-load LATENCY. 8 blocks/CU x 8 different m x 8KB = 64KB C footprint vs
// 32KB L1 -> ~50% miss -> ~200cyc L2 latency on the dependent dot chain,
// invariant to row count (loads shared) — matches R7==R8.
//
// R9 (K1 only; K2 bit-frozen from R4): stage C[m] in LDS once per block
// (coalesced 8KB read + ds_write_b128 x2), k-loop reads uniform-address
// ds_read_b128 (broadcast, conflict-free, no cache to thrash). 1 row/thread
// (R7 grid) keeps VGPR<=64 -> 8 waves/SIMD; LDS 8KB/block -> no occupancy hit.
// Bit-exact: staging copies words; P=xa*ca, Q=xb*cb, T=P+Q,
// dot=(T.x+T.y)+(T.z+T.w), contract off, strict > = first-max.

#define B_SZ   16384
#define FEAT   512
#define M_SZ   64
#define K_SZ   256
#define D_SZ   8

typedef float v4f __attribute__((ext_vector_type(4)));

// ---------------- K1: packed argmax, C[m] staged in LDS ----------------
// 4096 blocks x 256 threads; block = (m, chunk of 256 b); thread = one b.
__global__ __launch_bounds__(256) void pq_argmax(
    const float* __restrict__ x,
    const float* __restrict__ C,
    unsigned char* __restrict__ bestk8)   // [B][M]
{
#pragma clang fp contract(off)   // np einsum: separate product roundings, no FMA

    const int t     = threadIdx.x;
    const int m     = blockIdx.x & (M_SZ - 1);   // block-uniform m
    const int chunk = blockIdx.x >> 6;
    const int b     = (chunk << 8) | t;

    __shared__ v4f Cs[K_SZ * 2];   // 8KB; Cs[2k],Cs[2k+1] = row k (d0..3, d4..7)

    // Stage C[m]: thread t copies row t (32B). Global: contiguous 8KB/block,
    // fully coalesced. One-time cost, removes VMEM from the k-loop entirely.
    {
        const v4f* src = (const v4f*)(C + (size_t)m * (K_SZ * D_SZ)) + (t << 1);
        Cs[(t << 1) | 0] = src[0];
        Cs[(t << 1) | 1] = src[1];
    }

    const float* xp = x + (size_t)b * FEAT + m * D_SZ;
    const v4f xa = ((const v4f*)xp)[0];   // (x0..x3)
    const v4f xb = ((const v4f*)xp)[1];   // (x4..x7)

    __syncthreads();

    float best  = -INFINITY;
    int   bestk = 0;

#pragma unroll 4
    for (int k = 0; k < K_SZ; ++k) {
        const v4f ca = Cs[(k << 1) | 0];   // ds_read_b128, uniform addr -> broadcast
        const v4f cb = Cs[(k << 1) | 1];
        v4f P = xa * ca;                   // v_pk_mul_f32 x2
        v4f Q = xb * cb;                   // (s4..s7)
        v4f T = P + Q;                     // v_pk_add_f32 x2
        float dot = (T.x + T.y) + (T.z + T.w);   // np tree, exact order
        if (dot > best) { best = dot; bestk = k; }  // strict >: first max
    }

    bestk8[(size_t)b * M_SZ + m] = (unsigned char)bestk;  // L2 merges bytes
}

// ---------------- K2: fill-shaped writer (bit-frozen from R4) ----------------
// 4096 blocks x 256 threads; block owns b rows [4*blk, 4*blk+4) = 256 KB slab.
__global__ __launch_bounds__(256) void pq_fill(
    const float* __restrict__ C,
    const unsigned char* __restrict__ bestk8,  // [B][M]
    float* __restrict__ xhat,
    float* __restrict__ codes)
{
    const int t    = threadIdx.x;
    const int b0   = blockIdx.x << 2;
    const int w    = t >> 6;         // wave 0..3
    const int lane = t & 63;

    __shared__ unsigned char lbk[4 * M_SZ];

    lbk[t] = bestk8[(size_t)b0 * M_SZ + t];

    // xhat: wave w -> row b0+w, lane -> m. Coalesced 2KB/wave.
    {
        const int b  = b0 + w;
        const int kb = (int)bestk8[(size_t)b * M_SZ + lane];
        const float* cw = C + ((size_t)lane * K_SZ + kb) * D_SZ;
        const float4 h0 = ((const float4*)cw)[0];
        const float4 h1 = ((const float4*)cw)[1];
        float* xh = xhat + (size_t)b * FEAT + lane * D_SZ;
        ((float4*)xh)[0] = h0;
        ((float4*)xh)[1] = h1;
    }

    __syncthreads();

    // codes slab: 64 float4 stores/thread, one-hot folded in-stream.
    const int lane4 = lane << 2;
    float4* const slab = (float4*)(codes + (size_t)b0 * (M_SZ * K_SZ));

#pragma unroll 4
    for (int j = 0; j < 64; ++j) {
        const int r  = j >> 4;
        const int mj = (w + 4 * j) & 63;
        const int kk = (int)lbk[(r << 6) | mj];   // LDS broadcast (uniform)
        float4 v;
        v.x = (kk == lane4 + 0) ? 1.0f : 0.0f;
        v.y = (kk == lane4 + 1) ? 1.0f : 0.0f;
        v.z = (kk == lane4 + 2) ? 1.0f : 0.0f;
        v.w = (kk == lane4 + 3) ? 1.0f : 0.0f;
        slab[t + 256 * j] = v;
    }
}

extern "C" void kernel_launch(void* const* d_in, const int* in_sizes, int n_in,
                              void* d_out, int out_size, void* d_ws, size_t ws_size,
                              hipStream_t stream)
{
    const float* x = (const float*)d_in[0];
    const float* C = (const float*)d_in[1];
    float* xhat  = (float*)d_out;                           // (B, 512)
    float* codes = (float*)d_out + (size_t)B_SZ * FEAT;     // (B, 64, 256)
    unsigned char* bestk8 = (unsigned char*)d_ws;           // [B][M] u8 = 1 MB

    hipLaunchKernelGGL(pq_argmax, dim3(4096), dim3(256), 0, stream, x, C, bestk8);
    hipLaunchKernelGGL(pq_fill,   dim3(4096), dim3(256), 0, stream, C, bestk8, xhat, codes);
}

// Round 3
// 1149.429 us; speedup vs baseline: 1.0428x; 1.0380x over previous
//
#include <hip/hip_runtime.h>
#include <math.h>

// PQLayer forward, MI355X — R10: FUSED single kernel.
//   x: (B,512) fp32   C: (64,256,8) fp32
//   out0 x_hat (B,512) = C[m,k*,:]   out1 codes (B,64,256) = one_hot(k*)
//
// Model: dur = fill(~707us harness poison, HBM-floor) + t1 + t2 + gaps.
// R8 (ILP/VMEM cut) and R9 (LDS staging) both NEUTRAL -> K1 is not C-load
// latency bound (uniform C addrs were likely s_load/scalar-cache all along;
// R9's broadcast ds_reads have a ~160us port ceiling of their own = same
// size as what it replaced). Untouched lever: K1 and K2 are SERIAL in-stream
// with disjoint bottleneck pipes (t1 compute/LDS ~180, t2 write-BW ~200).
//
// R10: fuse. Block = (m block-uniform, 256 b-rows), as K1:
//   1. stage C[m] -> LDS (8KB, coalesced)           [R9, bit-frozen]
//   2. k-loop argmax from LDS                        [R9, bit-frozen]
//   3. xhat[b, m*8..+8) = Cs[2k*],Cs[2k*+1]          (32B/thread scatter;
//      line-halves merge in L2 with adjacent-m block)
//   4. lbk[t]=bestk, barrier
//   5. codes: wave w, iter j -> local row i=4j+w; 1KB contiguous wave-store
//      (64 lanes x float4 at b*16384+m*256 floats), one-hot folded in-stream.
// Deletes: 2nd launch, bestk8 HBM round-trip, K2's C/bestk reads, grid
// barrier. Blocks in phase 2 overlap with blocks in phase 5 across the chip
// -> serial t1+t2 becomes ~max(t1,t2).
// Bit-exact: staging copies words; P=xa*ca,Q=xb*cb,T=P+Q,
// dot=(T.x+T.y)+(T.z+T.w), contract off, strict > = first-max; one-hot via
// same 4-compare construction as frozen K2.

#define B_SZ   16384
#define FEAT   512
#define M_SZ   64
#define K_SZ   256
#define D_SZ   8

typedef float v4f __attribute__((ext_vector_type(4)));

// 4096 blocks x 256 threads; block = (m, chunk of 256 b); thread = one b.
__global__ __launch_bounds__(256) void pq_fused(
    const float* __restrict__ x,
    const float* __restrict__ C,
    float* __restrict__ xhat,
    float* __restrict__ codes)
{
#pragma clang fp contract(off)   // np einsum: separate product roundings, no FMA

    const int t     = threadIdx.x;
    const int m     = blockIdx.x & (M_SZ - 1);   // block-uniform m
    const int chunk = blockIdx.x >> 6;
    const int b     = (chunk << 8) | t;

    __shared__ v4f Cs[K_SZ * 2];            // 8KB; rows k: (d0..3),(d4..7)
    __shared__ unsigned char lbk[256];      // bestk per local row

    // ---- 1. stage C[m]: thread t copies row t (32B), coalesced 8KB ----
    {
        const v4f* src = (const v4f*)(C + (size_t)m * (K_SZ * D_SZ)) + (t << 1);
        Cs[(t << 1) | 0] = src[0];
        Cs[(t << 1) | 1] = src[1];
    }

    const float* xp = x + (size_t)b * FEAT + m * D_SZ;
    const v4f xa = ((const v4f*)xp)[0];   // (x0..x3)
    const v4f xb = ((const v4f*)xp)[1];   // (x4..x7)

    __syncthreads();

    // ---- 2. argmax over k (bit-exact R9 loop) ----
    float best  = -INFINITY;
    int   bestk = 0;

#pragma unroll 4
    for (int k = 0; k < K_SZ; ++k) {
        const v4f ca = Cs[(k << 1) | 0];   // uniform addr -> broadcast
        const v4f cb = Cs[(k << 1) | 1];
        v4f P = xa * ca;                   // v_pk_mul_f32 x2
        v4f Q = xb * cb;
        v4f T = P + Q;                     // v_pk_add_f32 x2
        float dot = (T.x + T.y) + (T.z + T.w);   // np tree, exact order
        if (dot > best) { best = dot; bestk = k; }  // strict >: first max
    }

    // ---- 3. xhat gather from LDS copy (same bits as global C) ----
    {
        const v4f h0 = Cs[(bestk << 1) | 0];
        const v4f h1 = Cs[(bestk << 1) | 1];
        float* xh = xhat + (size_t)b * FEAT + m * D_SZ;
        ((v4f*)xh)[0] = h0;
        ((v4f*)xh)[1] = h1;
    }

    // ---- 4. share bestk within block ----
    lbk[t] = (unsigned char)bestk;
    __syncthreads();

    // ---- 5. codes: 256 rows x 1KB one-hot, coalesced wave-stores ----
    const int w     = t >> 6;        // wave 0..3
    const int lane  = t & 63;
    const int lane4 = lane << 2;

#pragma unroll 4
    for (int j = 0; j < 64; ++j) {
        const int i  = (j << 2) | w;               // local row 0..255
        const int kk = (int)lbk[i];                // LDS broadcast (uniform)
        float4 v;
        v.x = (kk == lane4 + 0) ? 1.0f : 0.0f;
        v.y = (kk == lane4 + 1) ? 1.0f : 0.0f;
        v.z = (kk == lane4 + 2) ? 1.0f : 0.0f;
        v.w = (kk == lane4 + 3) ? 1.0f : 0.0f;
        // float4 index: b_row*4096 + m*64 + lane  (1KB contiguous per wave)
        const size_t f4 = ((size_t)((chunk << 8) | i) << 12) + (m << 6) + lane;
        ((float4*)codes)[f4] = v;
    }
}

extern "C" void kernel_launch(void* const* d_in, const int* in_sizes, int n_in,
                              void* d_out, int out_size, void* d_ws, size_t ws_size,
                              hipStream_t stream)
{
    const float* x = (const float*)d_in[0];
    const float* C = (const float*)d_in[1];
    float* xhat  = (float*)d_out;                           // (B, 512)
    float* codes = (float*)d_out + (size_t)B_SZ * FEAT;     // (B, 64, 256)

    hipLaunchKernelGGL(pq_fused, dim3(4096), dim3(256), 0, stream,
                       x, C, xhat, codes);
}